// Round 3
// baseline (412.861 us; speedup 1.0000x reference)
//
#include <hip/hip_runtime.h>

#define NN 100000   // nodes
#define NE 1000000  // edges
#define FD 64       // feature dim
#define NBLK 98     // scan blocks: ceil(NN/1024)

// ws layout (4-byte units):
//   deg      : [0, NN)               int   (in-degree)
//   cursor   : [NN, 2NN)             int   (build cursors, init = rowstart copy)
//   rowstart : [2NN, 3NN)            int   (CSR row offsets, exclusive scan of deg)
//   partial  : [3NN, 3NN+128)        int   (scan block sums)
//   csr      : [3NN+128, +NE)        int   (src ids grouped by dst)
//   pq       : [3NN+128+NE, +4NN)    float (p0,p1,q0,q1 per node)
// total = 7*NN + 128 + NE floats ≈ 6.8 MB

#define OFF_DEG 0
#define OFF_CUR (NN)
#define OFF_ROW (2 * NN)
#define OFF_PAR (3 * NN)
#define OFF_CSR (3 * NN + 128)
#define OFF_PQ  (3 * NN + 128 + NE)

// ---------------------------------------------------------------------------
// K1: in-degree counts (int atomics), int4-vectorized edge reads.
__global__ void k_prep(const int* __restrict__ ei, int* __restrict__ deg) {
    int stride = gridDim.x * blockDim.x;
    const int4* dst4 = (const int4*)(ei + NE);  // NE % 4 == 0
    for (int i = blockIdx.x * blockDim.x + threadIdx.x; i < NE / 4; i += stride) {
        int4 v = dst4[i];
        atomicAdd(&deg[v.x], 1);
        atomicAdd(&deg[v.y], 1);
        atomicAdd(&deg[v.z], 1);
        atomicAdd(&deg[v.w], 1);
    }
}

// ---------------------------------------------------------------------------
// K2a: per-block (1024-elem) sums of deg -> partial[b]
__global__ __launch_bounds__(256) void k_scanA(const int* __restrict__ deg,
                                               int* __restrict__ partial) {
    __shared__ int lds[256];
    int t = threadIdx.x;
    int base = blockIdx.x * 1024 + t * 4;
    int s_t = 0;
    if (base < NN) {  // NN % 4 == 0, so full int4 is safe
        int4 v = *(const int4*)(deg + base);
        s_t = v.x + v.y + v.z + v.w;
    }
    lds[t] = s_t;
    __syncthreads();
    for (int s = 128; s; s >>= 1) {
        if (t < s) lds[t] += lds[t + s];
        __syncthreads();
    }
    if (t == 0) partial[blockIdx.x] = lds[0];
}

// K2b: block offset + intra-block exclusive scan -> rowstart[i]
__global__ __launch_bounds__(256) void k_scanB(const int* __restrict__ deg,
                                               const int* __restrict__ partial,
                                               int* __restrict__ rowstart) {
    __shared__ int lds[256];
    int t = threadIdx.x, b = blockIdx.x;
    lds[t] = (t < b && t < NBLK) ? partial[t] : 0;
    __syncthreads();
    for (int s = 128; s; s >>= 1) {
        if (t < s) lds[t] += lds[t + s];
        __syncthreads();
    }
    int bo = lds[0];
    __syncthreads();

    int base = b * 1024 + t * 4;
    int4 v = make_int4(0, 0, 0, 0);
    if (base < NN) v = *(const int4*)(deg + base);
    int s_t = v.x + v.y + v.z + v.w;

    lds[t] = s_t;
    __syncthreads();
    for (int off = 1; off < 256; off <<= 1) {
        int v2 = lds[t];
        if (t >= off) v2 += lds[t - off];
        __syncthreads();
        lds[t] = v2;
        __syncthreads();
    }
    int excl = lds[t] - s_t;
    if (base < NN) {
        int r = bo + excl;
        int4 out;
        out.x = r;
        out.y = r + v.x;
        out.z = r + v.x + v.y;
        out.w = r + v.x + v.y + v.z;
        *(int4*)(rowstart + base) = out;
    }
}

// ---------------------------------------------------------------------------
// K3: scatter src into CSR slots (cursor pre-initialized to rowstart) and
//     write edge_index as float to the output tail (reads ei anyway).
__global__ void k_build(const int* __restrict__ ei, int* __restrict__ cursor,
                        int* __restrict__ csr, float* __restrict__ edge_out) {
    int stride = gridDim.x * blockDim.x;
    for (int e = blockIdx.x * blockDim.x + threadIdx.x; e < NE; e += stride) {
        int s = ei[e];
        int d = ei[NE + e];
        edge_out[e] = (float)s;
        edge_out[NE + e] = (float)d;
        int pos = atomicAdd(&cursor[d], 1);
        csr[pos] = s;
    }
}

// ---------------------------------------------------------------------------
// K4: fused layer-1 + projections. One wave per node (grid-stride):
//   lane f: acc_f = mean over neighbors of x[src][f]     (coalesced gather)
//   transpose acc row + self x row through per-wave LDS slot (broadcast reads)
//   lane k: h_k = relu(aggr@W1l^T[k] + x@W1r^T[k] + b1[k])
//   wave-reduce h@W2l^T, h@W2r^T + b2 -> pq[n] (float4)
__global__ __launch_bounds__(256) void k_l1(
    const int* __restrict__ csr, const int* __restrict__ rowstart,
    const int* __restrict__ deg, const float* __restrict__ x,
    const float* __restrict__ W1l, const float* __restrict__ b1,
    const float* __restrict__ W1r,
    const float* __restrict__ W2l, const float* __restrict__ b2,
    const float* __restrict__ W2r,
    float* __restrict__ pq) {
    __shared__ float srow[4][FD];
    __shared__ float xrow[4][FD];
    int lane = threadIdx.x & 63;
    int ws = threadIdx.x >> 6;
    int gw = (blockIdx.x * blockDim.x + threadIdx.x) >> 6;
    int nw = (gridDim.x * blockDim.x) >> 6;

    float wl[FD], wr[FD];
#pragma unroll
    for (int j = 0; j < FD; j += 4) {
        float4 a = *(const float4*)(W1l + lane * FD + j);
        wl[j] = a.x; wl[j + 1] = a.y; wl[j + 2] = a.z; wl[j + 3] = a.w;
        float4 c = *(const float4*)(W1r + lane * FD + j);
        wr[j] = c.x; wr[j + 1] = c.y; wr[j + 2] = c.z; wr[j + 3] = c.w;
    }
    float b1k = b1[lane];
    float w2l0 = W2l[lane], w2l1 = W2l[FD + lane];
    float w2r0 = W2r[lane], w2r1 = W2r[FD + lane];
    float b20 = b2[0], b21 = b2[1];

    for (int n = gw; n < NN; n += nw) {
        int rs = rowstart[n];
        int d = deg[n];
        float xv = x[(size_t)n * FD + lane];  // coalesced self row
        float acc = 0.f;
        int dm = min(d, 64);
        int srcj = (lane < dm) ? csr[rs + lane] : 0;
        for (int j = 0; j < dm; ++j) {
            int s = __shfl(srcj, j);
            acc += x[(size_t)s * FD + lane];
        }
        for (int e = rs + 64; e < rs + d; ++e) {  // deg>64 tail (rare)
            acc += x[(size_t)csr[e] * FD + lane];
        }
        float invc = 1.0f / (float)max(d, 1);
        srow[ws][lane] = acc * invc;
        xrow[ws][lane] = xv;
        // wave-private LDS RAW: ensure ds_writes land before broadcast reads
        asm volatile("s_waitcnt lgkmcnt(0)" ::: "memory");

        float accA = 0.f, accR = 0.f;
#pragma unroll
        for (int j4 = 0; j4 < FD / 4; ++j4) {
            float4 s = *(const float4*)(&srow[ws][4 * j4]);   // broadcast
            float4 xx = *(const float4*)(&xrow[ws][4 * j4]);  // broadcast
            accA += s.x * wl[4 * j4] + s.y * wl[4 * j4 + 1] +
                    s.z * wl[4 * j4 + 2] + s.w * wl[4 * j4 + 3];
            accR += xx.x * wr[4 * j4] + xx.y * wr[4 * j4 + 1] +
                    xx.z * wr[4 * j4 + 2] + xx.w * wr[4 * j4 + 3];
        }
        float h = fmaxf(accA + accR + b1k, 0.0f);

        float p0 = h * w2l0, p1 = h * w2l1;
        float q0 = h * w2r0, q1 = h * w2r1;
#pragma unroll
        for (int off = 32; off; off >>= 1) {
            p0 += __shfl_xor(p0, off);
            p1 += __shfl_xor(p1, off);
            q0 += __shfl_xor(q0, off);
            q1 += __shfl_xor(q1, off);
        }
        if (lane == 0)
            *(float4*)(pq + 4 * (size_t)n) = make_float4(p0, p1, q0 + b20, q1 + b21);
    }
}

// ---------------------------------------------------------------------------
// K5: layer-2 mean aggregation of p (8B gathers, L2/L3-resident) + final add.
__global__ void k_l2(const int* __restrict__ csr, const int* __restrict__ rowstart,
                     const int* __restrict__ deg, const float* __restrict__ pq,
                     float* __restrict__ out) {
    int n = blockIdx.x * blockDim.x + threadIdx.x;
    if (n >= NN) return;
    int rs = rowstart[n];
    int d = deg[n];
    float a0 = 0.f, a1 = 0.f;
    for (int i = 0; i < d; ++i) {
        int s = csr[rs + i];
        float2 v = *(const float2*)(pq + 4 * (size_t)s);
        a0 += v.x;
        a1 += v.y;
    }
    float inv = 1.0f / (float)max(d, 1);
    float2 q = *(const float2*)(pq + 4 * (size_t)n + 2);
    *(float2*)(out + 2 * (size_t)n) = make_float2(a0 * inv + q.x, a1 * inv + q.y);
}

// ---------------------------------------------------------------------------
extern "C" void kernel_launch(void* const* d_in, const int* in_sizes, int n_in,
                              void* d_out, int out_size, void* d_ws, size_t ws_size,
                              hipStream_t stream) {
    const float* x   = (const float*)d_in[0];
    const int*   ei  = (const int*)d_in[1];
    const float* W1l = (const float*)d_in[2];
    const float* b1  = (const float*)d_in[3];
    const float* W1r = (const float*)d_in[4];
    const float* W2l = (const float*)d_in[5];
    const float* b2  = (const float*)d_in[6];
    const float* W2r = (const float*)d_in[7];

    float* out      = (float*)d_out;   // N*2 floats
    float* edge_out = out + 2 * NN;    // 2*E floats (edge_index as float)

    int*   wsi      = (int*)d_ws;
    int*   deg      = wsi + OFF_DEG;
    int*   cursor   = wsi + OFF_CUR;
    int*   rowstart = wsi + OFF_ROW;
    int*   partial  = wsi + OFF_PAR;
    int*   csr      = wsi + OFF_CSR;
    float* pq       = (float*)d_ws + OFF_PQ;

    hipMemsetAsync(deg, 0, (size_t)NN * sizeof(int), stream);

    k_prep<<<1024, 256, 0, stream>>>(ei, deg);
    k_scanA<<<NBLK, 256, 0, stream>>>(deg, partial);
    k_scanB<<<NBLK, 256, 0, stream>>>(deg, partial, rowstart);
    hipMemcpyAsync(cursor, rowstart, (size_t)NN * sizeof(int),
                   hipMemcpyDeviceToDevice, stream);
    k_build<<<2048, 256, 0, stream>>>(ei, cursor, csr, edge_out);
    k_l1<<<2048, 256, 0, stream>>>(csr, rowstart, deg, x,
                                   W1l, b1, W1r, W2l, b2, W2r, pq);
    k_l2<<<(NN + 255) / 256, 256, 0, stream>>>(csr, rowstart, deg, pq, out);
}